// Round 1
// baseline (777.102 us; speedup 1.0000x reference)
//
#include <hip/hip_runtime.h>
#include <hip/hip_bf16.h>
#include <math.h>

// ---------------------------------------------------------------------------
// TernaryLeNet5 forward, fp32 baseline.
// Stages: ternarize -> conv1+tanh+pool -> conv2+tanh+pool -> conv3+tanh ->
//         fc1+tanh -> fc2 -> softmax.
// Weights are ternarized once into d_ws, TRANSPOSED to [k][oc] layout so the
// conv/fc inner loops get broadcast (conv) or coalesced (fc/conv3) reads.
// tanh(max(pool window)+b) == max(tanh(window+b)) since tanh is monotone.
// ---------------------------------------------------------------------------

#define TERN_BLOCK 256

// ---- ws layout (float offsets) --------------------------------------------
// q1t   [25][32]        800
// q2t   [800][64]       51200
// q3t   [1600][120]     192000
// fw1t  [120][84]       10080
// fw2t  [84][10]        840
// pooled1 [1024][32][14][14]  6422528
// pooled2 [1024][64][5][5]    1638400
// h3      [1024][120]         122880
static const size_t OFF_Q1T   = 0;
static const size_t OFF_Q2T   = 800;
static const size_t OFF_Q3T   = 52000;
static const size_t OFF_FW1T  = 244000;
static const size_t OFF_FW2T  = 254080;
static const size_t OFF_P1    = 254920;   // %4==0 -> 16B aligned
static const size_t OFF_P2    = 6677448;  // %4==0
static const size_t OFF_H3    = 8315848;
// total 8438728 floats = 33.8 MB

// ---------------------------------------------------------------------------
__device__ __forceinline__ float block_reduce_sum_256(float v, float* sbuf) {
    #pragma unroll
    for (int off = 32; off > 0; off >>= 1) v += __shfl_down(v, off);
    int wid = threadIdx.x >> 6;
    __syncthreads();                       // protect sbuf reuse across calls
    if ((threadIdx.x & 63) == 0) sbuf[wid] = v;
    __syncthreads();
    if (threadIdx.x == 0) sbuf[0] = sbuf[0] + sbuf[1] + sbuf[2] + sbuf[3];
    __syncthreads();
    return sbuf[0];
}

// One block per weight tensor. TWN ternarize + transpose to [k][O].
__global__ __launch_bounds__(TERN_BLOCK)
void ternarize_kernel(const float* w1, const float* w2, const float* w3,
                      const float* fw1, const float* fw2,
                      float* q1t, float* q2t, float* q3t,
                      float* fw1t, float* fw2t) {
    __shared__ float sbuf[4];
    const float* src; float* dst; int O, K;
    switch (blockIdx.x) {
        case 0: src = w1;  dst = q1t;  O = 32;  K = 25;   break;
        case 1: src = w2;  dst = q2t;  O = 64;  K = 800;  break;
        case 2: src = w3;  dst = q3t;  O = 120; K = 1600; break;
        case 3: src = fw1; dst = fw1t; O = 84;  K = 120;  break;
        default: src = fw2; dst = fw2t; O = 10; K = 84;   break;
    }
    const int n = O * K;
    const int t = threadIdx.x;

    float s = 0.f;
    for (int i = t; i < n; i += TERN_BLOCK) s += fabsf(src[i]);
    float total = block_reduce_sum_256(s, sbuf);
    float delta = 0.7f * total / (float)n;

    float s1 = 0.f, cnt = 0.f;
    for (int i = t; i < n; i += TERN_BLOCK) {
        float aw = fabsf(src[i]);
        if (aw > delta) { s1 += aw; cnt += 1.f; }
    }
    s1  = block_reduce_sum_256(s1, sbuf);
    cnt = block_reduce_sum_256(cnt, sbuf);
    float alpha = s1 / fmaxf(cnt, 1.0f);

    for (int i = t; i < n; i += TERN_BLOCK) {
        float w = src[i];
        float aw = fabsf(w);
        float q = (aw > delta) ? (w > 0.f ? alpha : -alpha) : 0.f;
        int o = i / K;
        int k = i - o * K;
        dst[k * O + o] = q;
    }
}

// ---------------------------------------------------------------------------
// conv1: x[1024,1,32,32] * q1t[25][32] -> tanh -> pool2 -> pooled1[1024,32,14,14]
// One block per image. Thread = (ocg of 4 oc) x (pool position slot).
__global__ __launch_bounds__(256)
void conv1_kernel(const float* __restrict__ x, const float* __restrict__ q1t,
                  const float* __restrict__ b1, float* __restrict__ pooled1) {
    const int n = blockIdx.x;
    __shared__ float sx[1024];   // 32x32 image
    __shared__ float sw[800];    // [25][32]
    const int t = threadIdx.x;
    {
        const float4* src = (const float4*)(x + (size_t)n * 1024);
        if (t < 256) ((float4*)sx)[t] = src[t];
        if (t < 200) ((float4*)sw)[t] = ((const float4*)q1t)[t];
    }
    __syncthreads();

    const int ocg  = t >> 5;        // 0..7 -> oc = ocg*4 .. +3
    const int pos0 = t & 31;
    float bias[4];
    #pragma unroll
    for (int o = 0; o < 4; ++o) bias[o] = b1[ocg * 4 + o];

    for (int pos = pos0; pos < 196; pos += 32) {
        const int ph = pos / 14, pw = pos - ph * 14;
        const int r0 = 2 * ph, c0 = 2 * pw;
        float acc[4][4] = {};
        const float4* wp = (const float4*)sw + ocg;   // stride 8 float4 per tap
        #pragma unroll
        for (int kh = 0; kh < 5; ++kh) {
            const float* xr = sx + (r0 + kh) * 32 + c0;
            #pragma unroll
            for (int kw = 0; kw < 5; ++kw) {
                const float4 w4 = *wp; wp += 8;
                const float x00 = xr[kw],      x01 = xr[kw + 1];
                const float x10 = xr[kw + 32], x11 = xr[kw + 33];
                acc[0][0] = fmaf(w4.x, x00, acc[0][0]);
                acc[0][1] = fmaf(w4.x, x01, acc[0][1]);
                acc[0][2] = fmaf(w4.x, x10, acc[0][2]);
                acc[0][3] = fmaf(w4.x, x11, acc[0][3]);
                acc[1][0] = fmaf(w4.y, x00, acc[1][0]);
                acc[1][1] = fmaf(w4.y, x01, acc[1][1]);
                acc[1][2] = fmaf(w4.y, x10, acc[1][2]);
                acc[1][3] = fmaf(w4.y, x11, acc[1][3]);
                acc[2][0] = fmaf(w4.z, x00, acc[2][0]);
                acc[2][1] = fmaf(w4.z, x01, acc[2][1]);
                acc[2][2] = fmaf(w4.z, x10, acc[2][2]);
                acc[2][3] = fmaf(w4.z, x11, acc[2][3]);
                acc[3][0] = fmaf(w4.w, x00, acc[3][0]);
                acc[3][1] = fmaf(w4.w, x01, acc[3][1]);
                acc[3][2] = fmaf(w4.w, x10, acc[3][2]);
                acc[3][3] = fmaf(w4.w, x11, acc[3][3]);
            }
        }
        #pragma unroll
        for (int o = 0; o < 4; ++o) {
            float m = fmaxf(fmaxf(acc[o][0], acc[o][1]),
                            fmaxf(acc[o][2], acc[o][3]));
            float v = tanhf(m + bias[o]);
            pooled1[((size_t)n * 32 + ocg * 4 + o) * 196 + pos] = v;
        }
    }
}

// ---------------------------------------------------------------------------
// conv2: pooled1[1024,32,14,14] * q2t[800][64] -> tanh -> pool2
//        -> pooled2[1024,64,5,5]
// Block = (n, oc-half of 32). Thread = 4 oc x one 2x2 pool window.
__global__ __launch_bounds__(256)
void conv2_kernel(const float* __restrict__ pooled1, const float* __restrict__ q2t,
                  const float* __restrict__ b2, float* __restrict__ pooled2) {
    const int bx = blockIdx.x;
    const int n = bx >> 1;
    const int half = bx & 1;
    __shared__ float sx[32 * 196];   // 25 KB
    const int t = threadIdx.x;
    {
        const float4* src = (const float4*)(pooled1 + (size_t)n * 6272);
        #pragma unroll
        for (int i = t; i < 1568; i += 256) ((float4*)sx)[i] = src[i];
    }
    __syncthreads();

    const int ocg = t >> 5;           // 0..7  -> 4 oc each = 32 oc
    const int pos = t & 31;           // valid < 25
    int ph = pos / 5, pw = pos - ph * 5;
    if (pos >= 25) { ph = 0; pw = 0; }   // keep addresses in-bounds, discard
    const int oc0 = half * 32 + ocg * 4;
    const int r0 = 2 * ph, c0 = 2 * pw;

    float acc[4][4] = {};
    const float4* wp = (const float4*)q2t + (half * 8 + ocg);  // row = 16 f4

    for (int ic = 0; ic < 32; ++ic) {
        const float* xb = sx + ic * 196;
        #pragma unroll
        for (int kh = 0; kh < 5; ++kh) {
            const float* xr = xb + (r0 + kh) * 14 + c0;
            #pragma unroll
            for (int kw = 0; kw < 5; ++kw) {
                const float4 w4 = *wp; wp += 16;
                const float x00 = xr[kw],      x01 = xr[kw + 1];
                const float x10 = xr[kw + 14], x11 = xr[kw + 15];
                acc[0][0] = fmaf(w4.x, x00, acc[0][0]);
                acc[0][1] = fmaf(w4.x, x01, acc[0][1]);
                acc[0][2] = fmaf(w4.x, x10, acc[0][2]);
                acc[0][3] = fmaf(w4.x, x11, acc[0][3]);
                acc[1][0] = fmaf(w4.y, x00, acc[1][0]);
                acc[1][1] = fmaf(w4.y, x01, acc[1][1]);
                acc[1][2] = fmaf(w4.y, x10, acc[1][2]);
                acc[1][3] = fmaf(w4.y, x11, acc[1][3]);
                acc[2][0] = fmaf(w4.z, x00, acc[2][0]);
                acc[2][1] = fmaf(w4.z, x01, acc[2][1]);
                acc[2][2] = fmaf(w4.z, x10, acc[2][2]);
                acc[2][3] = fmaf(w4.z, x11, acc[2][3]);
                acc[3][0] = fmaf(w4.w, x00, acc[3][0]);
                acc[3][1] = fmaf(w4.w, x01, acc[3][1]);
                acc[3][2] = fmaf(w4.w, x10, acc[3][2]);
                acc[3][3] = fmaf(w4.w, x11, acc[3][3]);
            }
        }
    }
    if (pos < 25) {
        #pragma unroll
        for (int o = 0; o < 4; ++o) {
            float m = fmaxf(fmaxf(acc[o][0], acc[o][1]),
                            fmaxf(acc[o][2], acc[o][3]));
            float v = tanhf(m + b2[oc0 + o]);
            pooled2[((size_t)n * 64 + oc0 + o) * 25 + ph * 5 + pw] = v;
        }
    }
}

// ---------------------------------------------------------------------------
// conv3: pooled2[1024,64,5,5] * q3t[1600][120] + tanh -> h3[1024,120]
// Block = 2 images, 128 threads (thread = oc, 120 active).
__global__ __launch_bounds__(128)
void conv3_kernel(const float* __restrict__ pooled2, const float* __restrict__ q3t,
                  const float* __restrict__ b3, float* __restrict__ h3) {
    const int n0 = blockIdx.x * 2;
    __shared__ float sx[2 * 1600];
    const int t = threadIdx.x;
    {
        const float4* src = (const float4*)(pooled2 + (size_t)n0 * 1600);
        #pragma unroll
        for (int i = t; i < 800; i += 128) ((float4*)sx)[i] = src[i];
    }
    __syncthreads();

    const int ocl = (t < 120) ? t : 119;
    float a0 = 0.f, a1 = 0.f;
    for (int k = 0; k < 1600; k += 4) {
        const float w0 = q3t[(k + 0) * 120 + ocl];
        const float w1 = q3t[(k + 1) * 120 + ocl];
        const float w2 = q3t[(k + 2) * 120 + ocl];
        const float w3 = q3t[(k + 3) * 120 + ocl];
        a0 = fmaf(w0, sx[k],     a0); a1 = fmaf(w0, sx[1600 + k],     a1);
        a0 = fmaf(w1, sx[k + 1], a0); a1 = fmaf(w1, sx[1600 + k + 1], a1);
        a0 = fmaf(w2, sx[k + 2], a0); a1 = fmaf(w2, sx[1600 + k + 2], a1);
        a0 = fmaf(w3, sx[k + 3], a0); a1 = fmaf(w3, sx[1600 + k + 3], a1);
    }
    if (t < 120) {
        const float b = b3[t];
        h3[(size_t)(n0 + 0) * 120 + t] = tanhf(a0 + b);
        h3[(size_t)(n0 + 1) * 120 + t] = tanhf(a1 + b);
    }
}

// ---------------------------------------------------------------------------
// fc1 + tanh + fc2 + softmax. Block per image.
// out[0:10240] = logits, out[10240:20480] = probs.
__global__ __launch_bounds__(128)
void fc_kernel(const float* __restrict__ h3, const float* __restrict__ fw1t,
               const float* __restrict__ fb1, const float* __restrict__ fw2t,
               const float* __restrict__ fb2, float* __restrict__ out) {
    const int n = blockIdx.x;
    __shared__ float sh[120];
    __shared__ float sh4[84];
    __shared__ float sl[10];
    const int t = threadIdx.x;
    if (t < 120) sh[t] = h3[(size_t)n * 120 + t];
    __syncthreads();
    if (t < 84) {
        float a = fb1[t];
        #pragma unroll 4
        for (int k = 0; k < 120; ++k) a = fmaf(fw1t[k * 84 + t], sh[k], a);
        sh4[t] = tanhf(a);
    }
    __syncthreads();
    if (t < 10) {
        float a = fb2[t];
        #pragma unroll 4
        for (int k = 0; k < 84; ++k) a = fmaf(fw2t[k * 10 + t], sh4[k], a);
        sl[t] = a;
        out[(size_t)n * 10 + t] = a;          // logits
    }
    __syncthreads();
    if (t < 10) {
        float m = -INFINITY;
        #pragma unroll
        for (int i = 0; i < 10; ++i) m = fmaxf(m, sl[i]);
        float s = 0.f;
        #pragma unroll
        for (int i = 0; i < 10; ++i) s += expf(sl[i] - m);
        out[10240 + (size_t)n * 10 + t] = expf(sl[t] - m) / s;
    }
}

// ---------------------------------------------------------------------------
extern "C" void kernel_launch(void* const* d_in, const int* in_sizes, int n_in,
                              void* d_out, int out_size, void* d_ws, size_t ws_size,
                              hipStream_t stream) {
    const float* x   = (const float*)d_in[0];
    const float* w1  = (const float*)d_in[1];
    const float* b1  = (const float*)d_in[2];
    const float* w2  = (const float*)d_in[3];
    const float* b2  = (const float*)d_in[4];
    const float* w3  = (const float*)d_in[5];
    const float* b3  = (const float*)d_in[6];
    const float* fw1 = (const float*)d_in[7];
    const float* fb1 = (const float*)d_in[8];
    const float* fw2 = (const float*)d_in[9];
    const float* fb2 = (const float*)d_in[10];

    float* ws = (float*)d_ws;
    float* q1t   = ws + OFF_Q1T;
    float* q2t   = ws + OFF_Q2T;
    float* q3t   = ws + OFF_Q3T;
    float* fw1t  = ws + OFF_FW1T;
    float* fw2t  = ws + OFF_FW2T;
    float* pooled1 = ws + OFF_P1;
    float* pooled2 = ws + OFF_P2;
    float* h3      = ws + OFF_H3;
    float* out = (float*)d_out;

    ternarize_kernel<<<5, TERN_BLOCK, 0, stream>>>(w1, w2, w3, fw1, fw2,
                                                   q1t, q2t, q3t, fw1t, fw2t);
    conv1_kernel<<<1024, 256, 0, stream>>>(x, q1t, b1, pooled1);
    conv2_kernel<<<2048, 256, 0, stream>>>(pooled1, q2t, b2, pooled2);
    conv3_kernel<<<512, 128, 0, stream>>>(pooled2, q3t, b3, h3);
    fc_kernel<<<1024, 128, 0, stream>>>(h3, fw1t, fb1, fw2t, fb2, out);
}

// Round 2
// 397.626 us; speedup vs baseline: 1.9544x; 1.9544x over previous
//
#include <hip/hip_runtime.h>
#include <hip/hip_bf16.h>
#include <math.h>

// ---------------------------------------------------------------------------
// TernaryLeNet5 forward, fp32.
// R1 change: ternarize was 5 blocks total -> ~500us latency-bound (65% of
// runtime, OccupancyPercent 0.06). Now split into 3 wide kernels (80 blocks)
// with block-reduce + one atomicAdd per block:
//   tern_reduce_abs  -> accAbs[t]    (sum |w|)
//   tern_reduce_mask -> accS1/accCnt (masked sum, count; delta from accAbs)
//   tern_quantize    -> q*t transposed [k][O] with alpha folded in
// Convs unchanged from R0 (passed, absmax 0.0).
// ---------------------------------------------------------------------------

// ---- ws layout (float offsets) --------------------------------------------
static const size_t OFF_Q1T   = 0;        // [25][32]
static const size_t OFF_Q2T   = 800;      // [800][64]
static const size_t OFF_Q3T   = 52000;    // [1600][120]
static const size_t OFF_FW1T  = 244000;   // [120][84]
static const size_t OFF_FW2T  = 254080;   // [84][10]
static const size_t OFF_P1    = 254920;   // [1024][32][14][14]
static const size_t OFF_P2    = 6677448;  // [1024][64][5][5]
static const size_t OFF_H3    = 8315848;  // [1024][120]
static const size_t OFF_ACC   = 8438728;  // accAbs[5], accS1[5], accCnt[5], pad
// total ~33.8 MB + 64 B

#define BLOCKS_PER_TENSOR 16

__device__ __forceinline__ void tensor_select(int tensor,
        const float* w1, const float* w2, const float* w3,
        const float* fw1, const float* fw2,
        const float*& src, int& O, int& K) {
    switch (tensor) {
        case 0: src = w1;  O = 32;  K = 25;   break;
        case 1: src = w2;  O = 64;  K = 800;  break;
        case 2: src = w3;  O = 120; K = 1600; break;
        case 3: src = fw1; O = 84;  K = 120;  break;
        default: src = fw2; O = 10; K = 84;   break;
    }
}

// block(256) reduce: returns total on thread 0 (garbage elsewhere)
__device__ __forceinline__ float block_sum_256(float v, float* sbuf) {
    #pragma unroll
    for (int off = 32; off > 0; off >>= 1) v += __shfl_down(v, off);
    const int wid = threadIdx.x >> 6;
    if ((threadIdx.x & 63) == 0) sbuf[wid] = v;
    __syncthreads();
    return sbuf[0] + sbuf[1] + sbuf[2] + sbuf[3];
}

__global__ __launch_bounds__(256)
void tern_reduce_abs(const float* w1, const float* w2, const float* w3,
                     const float* fw1, const float* fw2, float* acc) {
    __shared__ float sbuf[4];
    const int tensor = blockIdx.x / BLOCKS_PER_TENSOR;
    const int blk    = blockIdx.x % BLOCKS_PER_TENSOR;
    const float* src; int O, K;
    tensor_select(tensor, w1, w2, w3, fw1, fw2, src, O, K);
    const int n = O * K;
    float s = 0.f;
    for (int i = blk * 256 + threadIdx.x; i < n; i += BLOCKS_PER_TENSOR * 256)
        s += fabsf(src[i]);
    s = block_sum_256(s, sbuf);
    if (threadIdx.x == 0) atomicAdd(&acc[tensor], s);
}

__global__ __launch_bounds__(256)
void tern_reduce_mask(const float* w1, const float* w2, const float* w3,
                      const float* fw1, const float* fw2, float* acc) {
    __shared__ float sbuf[4];
    const int tensor = blockIdx.x / BLOCKS_PER_TENSOR;
    const int blk    = blockIdx.x % BLOCKS_PER_TENSOR;
    const float* src; int O, K;
    tensor_select(tensor, w1, w2, w3, fw1, fw2, src, O, K);
    const int n = O * K;
    const float delta = 0.7f * acc[tensor] / (float)n;
    float s1 = 0.f, cnt = 0.f;
    for (int i = blk * 256 + threadIdx.x; i < n; i += BLOCKS_PER_TENSOR * 256) {
        float aw = fabsf(src[i]);
        if (aw > delta) { s1 += aw; cnt += 1.f; }
    }
    s1 = block_sum_256(s1, sbuf);
    __syncthreads();
    cnt = block_sum_256(cnt, sbuf);
    if (threadIdx.x == 0) {
        atomicAdd(&acc[5 + tensor], s1);
        atomicAdd(&acc[10 + tensor], cnt);
    }
}

__global__ __launch_bounds__(256)
void tern_quantize(const float* w1, const float* w2, const float* w3,
                   const float* fw1, const float* fw2,
                   float* q1t, float* q2t, float* q3t,
                   float* fw1t, float* fw2t, const float* acc) {
    const int tensor = blockIdx.x / BLOCKS_PER_TENSOR;
    const int blk    = blockIdx.x % BLOCKS_PER_TENSOR;
    const float* src; int O, K;
    tensor_select(tensor, w1, w2, w3, fw1, fw2, src, O, K);
    float* dst;
    switch (tensor) {
        case 0: dst = q1t;  break;
        case 1: dst = q2t;  break;
        case 2: dst = q3t;  break;
        case 3: dst = fw1t; break;
        default: dst = fw2t; break;
    }
    const int n = O * K;
    const float delta = 0.7f * acc[tensor] / (float)n;
    const float alpha = acc[5 + tensor] / fmaxf(acc[10 + tensor], 1.0f);
    for (int i = blk * 256 + threadIdx.x; i < n; i += BLOCKS_PER_TENSOR * 256) {
        float w = src[i];
        float aw = fabsf(w);
        float q = (aw > delta) ? (w > 0.f ? alpha : -alpha) : 0.f;
        int o = i / K;
        int k = i - o * K;
        dst[k * O + o] = q;
    }
}

// ---------------------------------------------------------------------------
// conv1: x[1024,1,32,32] * q1t[25][32] -> tanh -> pool2 -> pooled1[1024,32,14,14]
__global__ __launch_bounds__(256)
void conv1_kernel(const float* __restrict__ x, const float* __restrict__ q1t,
                  const float* __restrict__ b1, float* __restrict__ pooled1) {
    const int n = blockIdx.x;
    __shared__ float sx[1024];   // 32x32 image
    __shared__ float sw[800];    // [25][32]
    const int t = threadIdx.x;
    {
        const float4* src = (const float4*)(x + (size_t)n * 1024);
        if (t < 256) ((float4*)sx)[t] = src[t];
        if (t < 200) ((float4*)sw)[t] = ((const float4*)q1t)[t];
    }
    __syncthreads();

    const int ocg  = t >> 5;        // 0..7 -> oc = ocg*4 .. +3
    const int pos0 = t & 31;
    float bias[4];
    #pragma unroll
    for (int o = 0; o < 4; ++o) bias[o] = b1[ocg * 4 + o];

    for (int pos = pos0; pos < 196; pos += 32) {
        const int ph = pos / 14, pw = pos - ph * 14;
        const int r0 = 2 * ph, c0 = 2 * pw;
        float acc[4][4] = {};
        const float4* wp = (const float4*)sw + ocg;
        #pragma unroll
        for (int kh = 0; kh < 5; ++kh) {
            const float* xr = sx + (r0 + kh) * 32 + c0;
            #pragma unroll
            for (int kw = 0; kw < 5; ++kw) {
                const float4 w4 = *wp; wp += 8;
                const float x00 = xr[kw],      x01 = xr[kw + 1];
                const float x10 = xr[kw + 32], x11 = xr[kw + 33];
                acc[0][0] = fmaf(w4.x, x00, acc[0][0]);
                acc[0][1] = fmaf(w4.x, x01, acc[0][1]);
                acc[0][2] = fmaf(w4.x, x10, acc[0][2]);
                acc[0][3] = fmaf(w4.x, x11, acc[0][3]);
                acc[1][0] = fmaf(w4.y, x00, acc[1][0]);
                acc[1][1] = fmaf(w4.y, x01, acc[1][1]);
                acc[1][2] = fmaf(w4.y, x10, acc[1][2]);
                acc[1][3] = fmaf(w4.y, x11, acc[1][3]);
                acc[2][0] = fmaf(w4.z, x00, acc[2][0]);
                acc[2][1] = fmaf(w4.z, x01, acc[2][1]);
                acc[2][2] = fmaf(w4.z, x10, acc[2][2]);
                acc[2][3] = fmaf(w4.z, x11, acc[2][3]);
                acc[3][0] = fmaf(w4.w, x00, acc[3][0]);
                acc[3][1] = fmaf(w4.w, x01, acc[3][1]);
                acc[3][2] = fmaf(w4.w, x10, acc[3][2]);
                acc[3][3] = fmaf(w4.w, x11, acc[3][3]);
            }
        }
        #pragma unroll
        for (int o = 0; o < 4; ++o) {
            float m = fmaxf(fmaxf(acc[o][0], acc[o][1]),
                            fmaxf(acc[o][2], acc[o][3]));
            float v = tanhf(m + bias[o]);
            pooled1[((size_t)n * 32 + ocg * 4 + o) * 196 + pos] = v;
        }
    }
}

// ---------------------------------------------------------------------------
// conv2: pooled1[1024,32,14,14] * q2t[800][64] -> tanh -> pool2
//        -> pooled2[1024,64,5,5]
__global__ __launch_bounds__(256)
void conv2_kernel(const float* __restrict__ pooled1, const float* __restrict__ q2t,
                  const float* __restrict__ b2, float* __restrict__ pooled2) {
    const int bx = blockIdx.x;
    const int n = bx >> 1;
    const int half = bx & 1;
    __shared__ float sx[32 * 196];   // 25 KB
    const int t = threadIdx.x;
    {
        const float4* src = (const float4*)(pooled1 + (size_t)n * 6272);
        #pragma unroll
        for (int i = t; i < 1568; i += 256) ((float4*)sx)[i] = src[i];
    }
    __syncthreads();

    const int ocg = t >> 5;           // 0..7  -> 4 oc each = 32 oc
    const int pos = t & 31;           // valid < 25
    int ph = pos / 5, pw = pos - ph * 5;
    if (pos >= 25) { ph = 0; pw = 0; }
    const int oc0 = half * 32 + ocg * 4;
    const int r0 = 2 * ph, c0 = 2 * pw;

    float acc[4][4] = {};
    const float4* wp = (const float4*)q2t + (half * 8 + ocg);  // row = 16 f4

    for (int ic = 0; ic < 32; ++ic) {
        const float* xb = sx + ic * 196;
        #pragma unroll
        for (int kh = 0; kh < 5; ++kh) {
            const float* xr = xb + (r0 + kh) * 14 + c0;
            #pragma unroll
            for (int kw = 0; kw < 5; ++kw) {
                const float4 w4 = *wp; wp += 16;
                const float x00 = xr[kw],      x01 = xr[kw + 1];
                const float x10 = xr[kw + 14], x11 = xr[kw + 15];
                acc[0][0] = fmaf(w4.x, x00, acc[0][0]);
                acc[0][1] = fmaf(w4.x, x01, acc[0][1]);
                acc[0][2] = fmaf(w4.x, x10, acc[0][2]);
                acc[0][3] = fmaf(w4.x, x11, acc[0][3]);
                acc[1][0] = fmaf(w4.y, x00, acc[1][0]);
                acc[1][1] = fmaf(w4.y, x01, acc[1][1]);
                acc[1][2] = fmaf(w4.y, x10, acc[1][2]);
                acc[1][3] = fmaf(w4.y, x11, acc[1][3]);
                acc[2][0] = fmaf(w4.z, x00, acc[2][0]);
                acc[2][1] = fmaf(w4.z, x01, acc[2][1]);
                acc[2][2] = fmaf(w4.z, x10, acc[2][2]);
                acc[2][3] = fmaf(w4.z, x11, acc[2][3]);
                acc[3][0] = fmaf(w4.w, x00, acc[3][0]);
                acc[3][1] = fmaf(w4.w, x01, acc[3][1]);
                acc[3][2] = fmaf(w4.w, x10, acc[3][2]);
                acc[3][3] = fmaf(w4.w, x11, acc[3][3]);
            }
        }
    }
    if (pos < 25) {
        #pragma unroll
        for (int o = 0; o < 4; ++o) {
            float m = fmaxf(fmaxf(acc[o][0], acc[o][1]),
                            fmaxf(acc[o][2], acc[o][3]));
            float v = tanhf(m + b2[oc0 + o]);
            pooled2[((size_t)n * 64 + oc0 + o) * 25 + ph * 5 + pw] = v;
        }
    }
}

// ---------------------------------------------------------------------------
// conv3: pooled2[1024,64,5,5] * q3t[1600][120] + tanh -> h3[1024,120]
__global__ __launch_bounds__(128)
void conv3_kernel(const float* __restrict__ pooled2, const float* __restrict__ q3t,
                  const float* __restrict__ b3, float* __restrict__ h3) {
    const int n0 = blockIdx.x * 2;
    __shared__ float sx[2 * 1600];
    const int t = threadIdx.x;
    {
        const float4* src = (const float4*)(pooled2 + (size_t)n0 * 1600);
        #pragma unroll
        for (int i = t; i < 800; i += 128) ((float4*)sx)[i] = src[i];
    }
    __syncthreads();

    const int ocl = (t < 120) ? t : 119;
    float a0 = 0.f, a1 = 0.f;
    for (int k = 0; k < 1600; k += 4) {
        const float w0 = q3t[(k + 0) * 120 + ocl];
        const float w1 = q3t[(k + 1) * 120 + ocl];
        const float w2 = q3t[(k + 2) * 120 + ocl];
        const float w3 = q3t[(k + 3) * 120 + ocl];
        a0 = fmaf(w0, sx[k],     a0); a1 = fmaf(w0, sx[1600 + k],     a1);
        a0 = fmaf(w1, sx[k + 1], a0); a1 = fmaf(w1, sx[1600 + k + 1], a1);
        a0 = fmaf(w2, sx[k + 2], a0); a1 = fmaf(w2, sx[1600 + k + 2], a1);
        a0 = fmaf(w3, sx[k + 3], a0); a1 = fmaf(w3, sx[1600 + k + 3], a1);
    }
    if (t < 120) {
        const float b = b3[t];
        h3[(size_t)(n0 + 0) * 120 + t] = tanhf(a0 + b);
        h3[(size_t)(n0 + 1) * 120 + t] = tanhf(a1 + b);
    }
}

// ---------------------------------------------------------------------------
// fc1 + tanh + fc2 + softmax. Block per image.
__global__ __launch_bounds__(128)
void fc_kernel(const float* __restrict__ h3, const float* __restrict__ fw1t,
               const float* __restrict__ fb1, const float* __restrict__ fw2t,
               const float* __restrict__ fb2, float* __restrict__ out) {
    const int n = blockIdx.x;
    __shared__ float sh[120];
    __shared__ float sh4[84];
    __shared__ float sl[10];
    const int t = threadIdx.x;
    if (t < 120) sh[t] = h3[(size_t)n * 120 + t];
    __syncthreads();
    if (t < 84) {
        float a = fb1[t];
        #pragma unroll 4
        for (int k = 0; k < 120; ++k) a = fmaf(fw1t[k * 84 + t], sh[k], a);
        sh4[t] = tanhf(a);
    }
    __syncthreads();
    if (t < 10) {
        float a = fb2[t];
        #pragma unroll 4
        for (int k = 0; k < 84; ++k) a = fmaf(fw2t[k * 10 + t], sh4[k], a);
        sl[t] = a;
        out[(size_t)n * 10 + t] = a;          // logits
    }
    __syncthreads();
    if (t < 10) {
        float m = -INFINITY;
        #pragma unroll
        for (int i = 0; i < 10; ++i) m = fmaxf(m, sl[i]);
        float s = 0.f;
        #pragma unroll
        for (int i = 0; i < 10; ++i) s += expf(sl[i] - m);
        out[10240 + (size_t)n * 10 + t] = expf(sl[t] - m) / s;
    }
}

// ---------------------------------------------------------------------------
extern "C" void kernel_launch(void* const* d_in, const int* in_sizes, int n_in,
                              void* d_out, int out_size, void* d_ws, size_t ws_size,
                              hipStream_t stream) {
    const float* x   = (const float*)d_in[0];
    const float* w1  = (const float*)d_in[1];
    const float* b1  = (const float*)d_in[2];
    const float* w2  = (const float*)d_in[3];
    const float* b2  = (const float*)d_in[4];
    const float* w3  = (const float*)d_in[5];
    const float* b3  = (const float*)d_in[6];
    const float* fw1 = (const float*)d_in[7];
    const float* fb1 = (const float*)d_in[8];
    const float* fw2 = (const float*)d_in[9];
    const float* fb2 = (const float*)d_in[10];

    float* ws = (float*)d_ws;
    float* q1t   = ws + OFF_Q1T;
    float* q2t   = ws + OFF_Q2T;
    float* q3t   = ws + OFF_Q3T;
    float* fw1t  = ws + OFF_FW1T;
    float* fw2t  = ws + OFF_FW2T;
    float* pooled1 = ws + OFF_P1;
    float* pooled2 = ws + OFF_P2;
    float* h3      = ws + OFF_H3;
    float* acc     = ws + OFF_ACC;
    float* out = (float*)d_out;

    // zero the 16-float accumulator region (graph-capture safe memset node)
    hipMemsetAsync(acc, 0, 16 * sizeof(float), stream);

    tern_reduce_abs <<<5 * BLOCKS_PER_TENSOR, 256, 0, stream>>>(w1, w2, w3, fw1, fw2, acc);
    tern_reduce_mask<<<5 * BLOCKS_PER_TENSOR, 256, 0, stream>>>(w1, w2, w3, fw1, fw2, acc);
    tern_quantize   <<<5 * BLOCKS_PER_TENSOR, 256, 0, stream>>>(w1, w2, w3, fw1, fw2,
                                                                q1t, q2t, q3t, fw1t, fw2t, acc);
    conv1_kernel<<<1024, 256, 0, stream>>>(x, q1t, b1, pooled1);
    conv2_kernel<<<2048, 256, 0, stream>>>(pooled1, q2t, b2, pooled2);
    conv3_kernel<<<512, 128, 0, stream>>>(pooled2, q3t, b3, h3);
    fc_kernel<<<1024, 128, 0, stream>>>(h3, fw1t, fb1, fw2t, fb2, out);
}

// Round 3
// 219.944 us; speedup vs baseline: 3.5332x; 1.8079x over previous
//
#include <hip/hip_runtime.h>
#include <hip/hip_bf16.h>
#include <math.h>

// ---------------------------------------------------------------------------
// TernaryLeNet5 forward.
// R2: conv2 rewritten as bf16 MFMA implicit GEMM (M=100 px, N=64 oc, K=800).
//   - conv1 stores pooled1 as bf16 NHWC [n][196][32] (p1h)
//   - ternarize stores conv2 weights as bf16 [oc][tap][ic] (w2b)
//   - conv2: stage image NHWC in LDS (stride 40 bf16 -> 2-way-max banks),
//     B preloaded in regs (2 phases, 13/12 taps), each wave = 2 n-tiles x
//     4 m-tiles, epilogue via LDS [oc][pix] f32 then pool+bias+tanh.
// conv3 / fc / reductions unchanged from R1.
// ---------------------------------------------------------------------------

typedef __attribute__((ext_vector_type(8))) short bf16x8;
typedef __attribute__((ext_vector_type(4))) float f32x4;

// ---- ws layout (float offsets) --------------------------------------------
static const size_t OFF_Q1T   = 0;        // [25][32] f32
static const size_t OFF_W2B   = 800;      // [64][25][32] bf16 = 25600 f32-slots
static const size_t OFF_Q3T   = 26400;    // [1600][120] f32
static const size_t OFF_FW1T  = 218400;   // [120][84] f32
static const size_t OFF_FW2T  = 228480;   // [84][10] f32
static const size_t OFF_P1H   = 229320;   // [1024][196][32] bf16 = 3211264 f32
static const size_t OFF_P2    = 3440584;  // [1024][64][5][5] f32
static const size_t OFF_H3    = 5078984;  // [1024][120] f32
static const size_t OFF_ACC   = 5201864;  // 16 f32
// total ~20.8 MB

#define BLOCKS_PER_TENSOR 16

__device__ __forceinline__ ushort f2bf(float v) {   // RNE float->bf16 bits
    unsigned u = __float_as_uint(v);
    unsigned r = (u + 0x7FFFu + ((u >> 16) & 1u)) >> 16;
    return (ushort)r;
}

__device__ __forceinline__ void tensor_select(int tensor,
        const float* w1, const float* w2, const float* w3,
        const float* fw1, const float* fw2,
        const float*& src, int& O, int& K) {
    switch (tensor) {
        case 0: src = w1;  O = 32;  K = 25;   break;
        case 1: src = w2;  O = 64;  K = 800;  break;
        case 2: src = w3;  O = 120; K = 1600; break;
        case 3: src = fw1; O = 84;  K = 120;  break;
        default: src = fw2; O = 10; K = 84;   break;
    }
}

__device__ __forceinline__ float block_sum_256(float v, float* sbuf) {
    #pragma unroll
    for (int off = 32; off > 0; off >>= 1) v += __shfl_down(v, off);
    const int wid = threadIdx.x >> 6;
    if ((threadIdx.x & 63) == 0) sbuf[wid] = v;
    __syncthreads();
    return sbuf[0] + sbuf[1] + sbuf[2] + sbuf[3];
}

__global__ __launch_bounds__(256)
void tern_reduce_abs(const float* w1, const float* w2, const float* w3,
                     const float* fw1, const float* fw2, float* acc) {
    __shared__ float sbuf[4];
    const int tensor = blockIdx.x / BLOCKS_PER_TENSOR;
    const int blk    = blockIdx.x % BLOCKS_PER_TENSOR;
    const float* src; int O, K;
    tensor_select(tensor, w1, w2, w3, fw1, fw2, src, O, K);
    const int n = O * K;
    float s = 0.f;
    for (int i = blk * 256 + threadIdx.x; i < n; i += BLOCKS_PER_TENSOR * 256)
        s += fabsf(src[i]);
    s = block_sum_256(s, sbuf);
    if (threadIdx.x == 0) atomicAdd(&acc[tensor], s);
}

__global__ __launch_bounds__(256)
void tern_reduce_mask(const float* w1, const float* w2, const float* w3,
                      const float* fw1, const float* fw2, float* acc) {
    __shared__ float sbuf[4];
    const int tensor = blockIdx.x / BLOCKS_PER_TENSOR;
    const int blk    = blockIdx.x % BLOCKS_PER_TENSOR;
    const float* src; int O, K;
    tensor_select(tensor, w1, w2, w3, fw1, fw2, src, O, K);
    const int n = O * K;
    const float delta = 0.7f * acc[tensor] / (float)n;
    float s1 = 0.f, cnt = 0.f;
    for (int i = blk * 256 + threadIdx.x; i < n; i += BLOCKS_PER_TENSOR * 256) {
        float aw = fabsf(src[i]);
        if (aw > delta) { s1 += aw; cnt += 1.f; }
    }
    s1 = block_sum_256(s1, sbuf);
    __syncthreads();
    cnt = block_sum_256(cnt, sbuf);
    if (threadIdx.x == 0) {
        atomicAdd(&acc[5 + tensor], s1);
        atomicAdd(&acc[10 + tensor], cnt);
    }
}

__global__ __launch_bounds__(256)
void tern_quantize(const float* w1, const float* w2, const float* w3,
                   const float* fw1, const float* fw2,
                   float* q1t, ushort* w2b, float* q3t,
                   float* fw1t, float* fw2t, const float* acc) {
    const int tensor = blockIdx.x / BLOCKS_PER_TENSOR;
    const int blk    = blockIdx.x % BLOCKS_PER_TENSOR;
    const float* src; int O, K;
    tensor_select(tensor, w1, w2, w3, fw1, fw2, src, O, K);
    const int n = O * K;
    const float delta = 0.7f * acc[tensor] / (float)n;
    const float alpha = acc[5 + tensor] / fmaxf(acc[10 + tensor], 1.0f);

    if (tensor == 1) {
        // conv2 weights -> bf16 [oc][tap][ic]; src is [oc][ic][kh][kw]
        for (int i = blk * 256 + threadIdx.x; i < n; i += BLOCKS_PER_TENSOR * 256) {
            float w = src[i];
            float aw = fabsf(w);
            float q = (aw > delta) ? (w > 0.f ? alpha : -alpha) : 0.f;
            int oc = i / 800;
            int r  = i - oc * 800;
            int ic = r / 25;
            int tap = r - ic * 25;
            w2b[oc * 800 + tap * 32 + ic] = f2bf(q);
        }
        return;
    }
    float* dst;
    switch (tensor) {
        case 0: dst = q1t;  break;
        case 2: dst = q3t;  break;
        case 3: dst = fw1t; break;
        default: dst = fw2t; break;
    }
    for (int i = blk * 256 + threadIdx.x; i < n; i += BLOCKS_PER_TENSOR * 256) {
        float w = src[i];
        float aw = fabsf(w);
        float q = (aw > delta) ? (w > 0.f ? alpha : -alpha) : 0.f;
        int o = i / K;
        int k = i - o * K;
        dst[k * O + o] = q;
    }
}

// ---------------------------------------------------------------------------
// conv1: x[1024,1,32,32] * q1t[25][32] -> tanh -> pool2
//        -> p1h bf16 NHWC [n][196][32]
__global__ __launch_bounds__(256)
void conv1_kernel(const float* __restrict__ x, const float* __restrict__ q1t,
                  const float* __restrict__ b1, ushort* __restrict__ p1h) {
    const int n = blockIdx.x;
    __shared__ float sx[1024];
    __shared__ float sw[800];
    const int t = threadIdx.x;
    {
        const float4* src = (const float4*)(x + (size_t)n * 1024);
        if (t < 256) ((float4*)sx)[t] = src[t];
        if (t < 200) ((float4*)sw)[t] = ((const float4*)q1t)[t];
    }
    __syncthreads();

    const int ocg  = t >> 5;
    const int pos0 = t & 31;
    float bias[4];
    #pragma unroll
    for (int o = 0; o < 4; ++o) bias[o] = b1[ocg * 4 + o];

    for (int pos = pos0; pos < 196; pos += 32) {
        const int ph = pos / 14, pw = pos - ph * 14;
        const int r0 = 2 * ph, c0 = 2 * pw;
        float acc[4][4] = {};
        const float4* wp = (const float4*)sw + ocg;
        #pragma unroll
        for (int kh = 0; kh < 5; ++kh) {
            const float* xr = sx + (r0 + kh) * 32 + c0;
            #pragma unroll
            for (int kw = 0; kw < 5; ++kw) {
                const float4 w4 = *wp; wp += 8;
                const float x00 = xr[kw],      x01 = xr[kw + 1];
                const float x10 = xr[kw + 32], x11 = xr[kw + 33];
                acc[0][0] = fmaf(w4.x, x00, acc[0][0]);
                acc[0][1] = fmaf(w4.x, x01, acc[0][1]);
                acc[0][2] = fmaf(w4.x, x10, acc[0][2]);
                acc[0][3] = fmaf(w4.x, x11, acc[0][3]);
                acc[1][0] = fmaf(w4.y, x00, acc[1][0]);
                acc[1][1] = fmaf(w4.y, x01, acc[1][1]);
                acc[1][2] = fmaf(w4.y, x10, acc[1][2]);
                acc[1][3] = fmaf(w4.y, x11, acc[1][3]);
                acc[2][0] = fmaf(w4.z, x00, acc[2][0]);
                acc[2][1] = fmaf(w4.z, x01, acc[2][1]);
                acc[2][2] = fmaf(w4.z, x10, acc[2][2]);
                acc[2][3] = fmaf(w4.z, x11, acc[2][3]);
                acc[3][0] = fmaf(w4.w, x00, acc[3][0]);
                acc[3][1] = fmaf(w4.w, x01, acc[3][1]);
                acc[3][2] = fmaf(w4.w, x10, acc[3][2]);
                acc[3][3] = fmaf(w4.w, x11, acc[3][3]);
            }
        }
        ushort4 qv;
        {
            float m0 = fmaxf(fmaxf(acc[0][0], acc[0][1]), fmaxf(acc[0][2], acc[0][3]));
            float m1 = fmaxf(fmaxf(acc[1][0], acc[1][1]), fmaxf(acc[1][2], acc[1][3]));
            float m2 = fmaxf(fmaxf(acc[2][0], acc[2][1]), fmaxf(acc[2][2], acc[2][3]));
            float m3 = fmaxf(fmaxf(acc[3][0], acc[3][1]), fmaxf(acc[3][2], acc[3][3]));
            qv.x = f2bf(tanhf(m0 + bias[0]));
            qv.y = f2bf(tanhf(m1 + bias[1]));
            qv.z = f2bf(tanhf(m2 + bias[2]));
            qv.w = f2bf(tanhf(m3 + bias[3]));
        }
        *(ushort4*)(p1h + ((size_t)n * 196 + pos) * 32 + ocg * 4) = qv;
    }
}

// ---------------------------------------------------------------------------
// conv2 as MFMA implicit GEMM.
// A: [100 px][800], from LDS NHWC tile (stride 40 bf16). One tap == one
// K-step of 32 (ic). B: w2b [oc][tap][ic] bf16, preloaded in regs.
// Wave w: n-pair base (w&1)*32 -> n-tiles {n0, n0+16}; m-tiles (w>>1)*4 .. +3
// (tile 7 is padding, reads clamped / writes guarded).
template<int TBASE, int TCNT>
__device__ __forceinline__ void conv2_phase(
        const ushort* __restrict__ w2b, const ushort* sxt,
        int n0, int mt0, int lane, f32x4 acc[4][2]) {
    const int col = lane & 15, quad = lane >> 4;
    bf16x8 bfr[TCNT][2];
    #pragma unroll
    for (int i = 0; i < TCNT; ++i) {
        const int tap = TBASE + i;
        #pragma unroll
        for (int np = 0; np < 2; ++np) {
            const int oc = n0 + np * 16 + col;
            bfr[i][np] = *(const bf16x8*)(w2b + (oc * 25 + tap) * 32 + quad * 8);
        }
    }
    #pragma unroll
    for (int mi = 0; mi < 4; ++mi) {
        int m = (mt0 + mi) * 16 + col;
        m = m < 100 ? m : 99;                      // clamp padding rows
        const int oh = m / 10, ow = m - oh * 10;
        const ushort* abase = sxt + (oh * 14 + ow) * 40 + quad * 8;
        #pragma unroll
        for (int i = 0; i < TCNT; ++i) {
            const int tap = TBASE + i;
            const int kh = tap / 5, kw = tap - kh * 5;
            bf16x8 af = *(const bf16x8*)(abase + (kh * 14 + kw) * 40);
            acc[mi][0] = __builtin_amdgcn_mfma_f32_16x16x32_bf16(af, bfr[i][0], acc[mi][0], 0, 0, 0);
            acc[mi][1] = __builtin_amdgcn_mfma_f32_16x16x32_bf16(af, bfr[i][1], acc[mi][1], 0, 0, 0);
        }
    }
}

__global__ __launch_bounds__(256)
void conv2_mfma(const ushort* __restrict__ p1h, const ushort* __restrict__ w2b,
                const float* __restrict__ b2, float* __restrict__ pooled2) {
    __shared__ ushort sxt[196 * 40];   // 15680 B, stride 40 = 2-way-max banks
    __shared__ float  cbuf[64 * 100];  // 25600 B, conv out [oc][pix]
    const int n = blockIdx.x;
    const int t = threadIdx.x;

    {   // stage NHWC image tile: 784 x 16B chunks
        const float4* src = (const float4*)(p1h + (size_t)n * 6272);
        for (int c = t; c < 784; c += 256) {
            const int pix = c >> 2, icq = c & 3;
            *(float4*)(&sxt[pix * 40 + icq * 8]) = src[c];
        }
    }
    __syncthreads();

    const int wave = t >> 6, lane = t & 63;
    const int n0  = (wave & 1) * 32;
    const int mt0 = (wave >> 1) * 4;
    f32x4 acc[4][2] = {};

    conv2_phase<0, 13>(w2b, sxt, n0, mt0, lane, acc);
    conv2_phase<13, 12>(w2b, sxt, n0, mt0, lane, acc);

    // C -> LDS [oc][pix]; lane holds rows m..m+3 (contig) for col = lane&15
    {
        const int col = lane & 15, quad = lane >> 4;
        #pragma unroll
        for (int mi = 0; mi < 4; ++mi) {
            const int mrow = (mt0 + mi) * 16 + quad * 4;
            if (mrow < 100) {
                #pragma unroll
                for (int np = 0; np < 2; ++np) {
                    const int oc = n0 + np * 16 + col;
                    *(f32x4*)(&cbuf[oc * 100 + mrow]) = acc[mi][np];
                }
            }
        }
    }
    __syncthreads();

    // pool 2x2 + bias + tanh -> pooled2 [n][oc][5][5] f32
    for (int idx = t; idx < 1600; idx += 256) {
        const int oc = idx / 25, r = idx - oc * 25;
        const int ph = r / 5, pw = r - ph * 5;
        const float* c0 = &cbuf[oc * 100 + ph * 20 + pw * 2];
        float m = fmaxf(fmaxf(c0[0], c0[1]), fmaxf(c0[10], c0[11]));
        pooled2[((size_t)n * 64 + oc) * 25 + r] = tanhf(m + b2[oc]);
    }
}

// ---------------------------------------------------------------------------
// conv3: pooled2[1024,64,5,5] * q3t[1600][120] + tanh -> h3[1024,120]
__global__ __launch_bounds__(128)
void conv3_kernel(const float* __restrict__ pooled2, const float* __restrict__ q3t,
                  const float* __restrict__ b3, float* __restrict__ h3) {
    const int n0 = blockIdx.x * 2;
    __shared__ float sx[2 * 1600];
    const int t = threadIdx.x;
    {
        const float4* src = (const float4*)(pooled2 + (size_t)n0 * 1600);
        #pragma unroll
        for (int i = t; i < 800; i += 128) ((float4*)sx)[i] = src[i];
    }
    __syncthreads();

    const int ocl = (t < 120) ? t : 119;
    float a0 = 0.f, a1 = 0.f;
    for (int k = 0; k < 1600; k += 4) {
        const float w0 = q3t[(k + 0) * 120 + ocl];
        const float w1 = q3t[(k + 1) * 120 + ocl];
        const float w2 = q3t[(k + 2) * 120 + ocl];
        const float w3 = q3t[(k + 3) * 120 + ocl];
        a0 = fmaf(w0, sx[k],     a0); a1 = fmaf(w0, sx[1600 + k],     a1);
        a0 = fmaf(w1, sx[k + 1], a0); a1 = fmaf(w1, sx[1600 + k + 1], a1);
        a0 = fmaf(w2, sx[k + 2], a0); a1 = fmaf(w2, sx[1600 + k + 2], a1);
        a0 = fmaf(w3, sx[k + 3], a0); a1 = fmaf(w3, sx[1600 + k + 3], a1);
    }
    if (t < 120) {
        const float b = b3[t];
        h3[(size_t)(n0 + 0) * 120 + t] = tanhf(a0 + b);
        h3[(size_t)(n0 + 1) * 120 + t] = tanhf(a1 + b);
    }
}

// ---------------------------------------------------------------------------
__global__ __launch_bounds__(128)
void fc_kernel(const float* __restrict__ h3, const float* __restrict__ fw1t,
               const float* __restrict__ fb1, const float* __restrict__ fw2t,
               const float* __restrict__ fb2, float* __restrict__ out) {
    const int n = blockIdx.x;
    __shared__ float sh[120];
    __shared__ float sh4[84];
    __shared__ float sl[10];
    const int t = threadIdx.x;
    if (t < 120) sh[t] = h3[(size_t)n * 120 + t];
    __syncthreads();
    if (t < 84) {
        float a = fb1[t];
        #pragma unroll 4
        for (int k = 0; k < 120; ++k) a = fmaf(fw1t[k * 84 + t], sh[k], a);
        sh4[t] = tanhf(a);
    }
    __syncthreads();
    if (t < 10) {
        float a = fb2[t];
        #pragma unroll 4
        for (int k = 0; k < 84; ++k) a = fmaf(fw2t[k * 10 + t], sh4[k], a);
        sl[t] = a;
        out[(size_t)n * 10 + t] = a;
    }
    __syncthreads();
    if (t < 10) {
        float m = -INFINITY;
        #pragma unroll
        for (int i = 0; i < 10; ++i) m = fmaxf(m, sl[i]);
        float s = 0.f;
        #pragma unroll
        for (int i = 0; i < 10; ++i) s += expf(sl[i] - m);
        out[10240 + (size_t)n * 10 + t] = expf(sl[t] - m) / s;
    }
}

// ---------------------------------------------------------------------------
extern "C" void kernel_launch(void* const* d_in, const int* in_sizes, int n_in,
                              void* d_out, int out_size, void* d_ws, size_t ws_size,
                              hipStream_t stream) {
    const float* x   = (const float*)d_in[0];
    const float* w1  = (const float*)d_in[1];
    const float* b1  = (const float*)d_in[2];
    const float* w2  = (const float*)d_in[3];
    const float* b2  = (const float*)d_in[4];
    const float* w3  = (const float*)d_in[5];
    const float* b3  = (const float*)d_in[6];
    const float* fw1 = (const float*)d_in[7];
    const float* fb1 = (const float*)d_in[8];
    const float* fw2 = (const float*)d_in[9];
    const float* fb2 = (const float*)d_in[10];

    float* ws = (float*)d_ws;
    float*  q1t  = ws + OFF_Q1T;
    ushort* w2b  = (ushort*)(ws + OFF_W2B);
    float*  q3t  = ws + OFF_Q3T;
    float*  fw1t = ws + OFF_FW1T;
    float*  fw2t = ws + OFF_FW2T;
    ushort* p1h  = (ushort*)(ws + OFF_P1H);
    float*  pooled2 = ws + OFF_P2;
    float*  h3   = ws + OFF_H3;
    float*  acc  = ws + OFF_ACC;
    float*  out  = (float*)d_out;

    hipMemsetAsync(acc, 0, 16 * sizeof(float), stream);

    tern_reduce_abs <<<5 * BLOCKS_PER_TENSOR, 256, 0, stream>>>(w1, w2, w3, fw1, fw2, acc);
    tern_reduce_mask<<<5 * BLOCKS_PER_TENSOR, 256, 0, stream>>>(w1, w2, w3, fw1, fw2, acc);
    tern_quantize   <<<5 * BLOCKS_PER_TENSOR, 256, 0, stream>>>(w1, w2, w3, fw1, fw2,
                                                                q1t, w2b, q3t, fw1t, fw2t, acc);
    conv1_kernel<<<1024, 256, 0, stream>>>(x, q1t, b1, p1h);
    conv2_mfma  <<<1024, 256, 0, stream>>>(p1h, w2b, b2, pooled2);
    conv3_kernel<<<512, 128, 0, stream>>>(pooled2, q3t, b3, h3);
    fc_kernel   <<<1024, 128, 0, stream>>>(h3, fw1t, fb1, fw2t, fb2, out);
}

// Round 4
// 176.076 us; speedup vs baseline: 4.4134x; 1.2491x over previous
//
#include <hip/hip_runtime.h>
#include <hip/hip_bf16.h>
#include <math.h>

// ---------------------------------------------------------------------------
// TernaryLeNet5 forward.
// R3: conv3 rewritten as bf16 MFMA GEMM (M=1024 img, N=120 oc, K=1600).
//   - conv2 epilogue emits p2b bf16 [n][1600] (k = oc*25 + pix, which matches
//     w3's [ic][kh][kw] K-order exactly)
//   - ternarize emits w3b bf16 [oc][1600] (pad to 128 rows, reads discarded)
//   - conv3_mfma: 256 blocks = 64 m-tiles x 4 oc-pairs; 4 waves split K
//     13/13/12/12 steps; frags straight from global (L2-resident);
//     cross-wave K-reduce via LDS; bias+tanh -> h3 f32.
// conv1 / conv2-core / fc / reductions unchanged from R2.
// ---------------------------------------------------------------------------

typedef __attribute__((ext_vector_type(8))) short bf16x8;
typedef __attribute__((ext_vector_type(4))) float f32x4;

// ---- ws layout (float offsets) --------------------------------------------
static const size_t OFF_Q1T   = 0;        // [25][32] f32
static const size_t OFF_W2B   = 800;      // [64][25][32] bf16   = 25600 f32
static const size_t OFF_W3B   = 26400;    // [128][1600] bf16    = 102400 f32
static const size_t OFF_FW1T  = 128800;   // [120][84] f32
static const size_t OFF_FW2T  = 138880;   // [84][10] f32
static const size_t OFF_P1H   = 139720;   // [1024][196][32] bf16 = 3211264 f32
static const size_t OFF_P2B   = 3350984;  // [1024][1600] bf16   = 819200 f32
static const size_t OFF_H3    = 4170184;  // [1024][120] f32
static const size_t OFF_ACC   = 4293064;  // 16 f32
// total ~17.2 MB

#define BLOCKS_PER_TENSOR 16

__device__ __forceinline__ ushort f2bf(float v) {   // RNE float->bf16 bits
    unsigned u = __float_as_uint(v);
    unsigned r = (u + 0x7FFFu + ((u >> 16) & 1u)) >> 16;
    return (ushort)r;
}

__device__ __forceinline__ void tensor_select(int tensor,
        const float* w1, const float* w2, const float* w3,
        const float* fw1, const float* fw2,
        const float*& src, int& O, int& K) {
    switch (tensor) {
        case 0: src = w1;  O = 32;  K = 25;   break;
        case 1: src = w2;  O = 64;  K = 800;  break;
        case 2: src = w3;  O = 120; K = 1600; break;
        case 3: src = fw1; O = 84;  K = 120;  break;
        default: src = fw2; O = 10; K = 84;   break;
    }
}

__device__ __forceinline__ float block_sum_256(float v, float* sbuf) {
    #pragma unroll
    for (int off = 32; off > 0; off >>= 1) v += __shfl_down(v, off);
    const int wid = threadIdx.x >> 6;
    if ((threadIdx.x & 63) == 0) sbuf[wid] = v;
    __syncthreads();
    return sbuf[0] + sbuf[1] + sbuf[2] + sbuf[3];
}

__global__ __launch_bounds__(256)
void tern_reduce_abs(const float* w1, const float* w2, const float* w3,
                     const float* fw1, const float* fw2, float* acc) {
    __shared__ float sbuf[4];
    const int tensor = blockIdx.x / BLOCKS_PER_TENSOR;
    const int blk    = blockIdx.x % BLOCKS_PER_TENSOR;
    const float* src; int O, K;
    tensor_select(tensor, w1, w2, w3, fw1, fw2, src, O, K);
    const int n = O * K;
    float s = 0.f;
    for (int i = blk * 256 + threadIdx.x; i < n; i += BLOCKS_PER_TENSOR * 256)
        s += fabsf(src[i]);
    s = block_sum_256(s, sbuf);
    if (threadIdx.x == 0) atomicAdd(&acc[tensor], s);
}

__global__ __launch_bounds__(256)
void tern_reduce_mask(const float* w1, const float* w2, const float* w3,
                      const float* fw1, const float* fw2, float* acc) {
    __shared__ float sbuf[4];
    const int tensor = blockIdx.x / BLOCKS_PER_TENSOR;
    const int blk    = blockIdx.x % BLOCKS_PER_TENSOR;
    const float* src; int O, K;
    tensor_select(tensor, w1, w2, w3, fw1, fw2, src, O, K);
    const int n = O * K;
    const float delta = 0.7f * acc[tensor] / (float)n;
    float s1 = 0.f, cnt = 0.f;
    for (int i = blk * 256 + threadIdx.x; i < n; i += BLOCKS_PER_TENSOR * 256) {
        float aw = fabsf(src[i]);
        if (aw > delta) { s1 += aw; cnt += 1.f; }
    }
    s1 = block_sum_256(s1, sbuf);
    __syncthreads();
    cnt = block_sum_256(cnt, sbuf);
    if (threadIdx.x == 0) {
        atomicAdd(&acc[5 + tensor], s1);
        atomicAdd(&acc[10 + tensor], cnt);
    }
}

__global__ __launch_bounds__(256)
void tern_quantize(const float* w1, const float* w2, const float* w3,
                   const float* fw1, const float* fw2,
                   float* q1t, ushort* w2b, ushort* w3b,
                   float* fw1t, float* fw2t, const float* acc) {
    const int tensor = blockIdx.x / BLOCKS_PER_TENSOR;
    const int blk    = blockIdx.x % BLOCKS_PER_TENSOR;
    const float* src; int O, K;
    tensor_select(tensor, w1, w2, w3, fw1, fw2, src, O, K);
    const int n = O * K;
    const float delta = 0.7f * acc[tensor] / (float)n;
    const float alpha = acc[5 + tensor] / fmaxf(acc[10 + tensor], 1.0f);

    if (tensor == 1) {
        // conv2 weights -> bf16 [oc][tap][ic]; src is [oc][ic][kh][kw]
        for (int i = blk * 256 + threadIdx.x; i < n; i += BLOCKS_PER_TENSOR * 256) {
            float w = src[i];
            float aw = fabsf(w);
            float q = (aw > delta) ? (w > 0.f ? alpha : -alpha) : 0.f;
            int oc = i / 800;
            int r  = i - oc * 800;
            int ic = r / 25;
            int tap = r - ic * 25;
            w2b[oc * 800 + tap * 32 + ic] = f2bf(q);
        }
        return;
    }
    if (tensor == 2) {
        // conv3 weights -> bf16 [oc][1600], same element order as source
        for (int i = blk * 256 + threadIdx.x; i < n; i += BLOCKS_PER_TENSOR * 256) {
            float w = src[i];
            float aw = fabsf(w);
            float q = (aw > delta) ? (w > 0.f ? alpha : -alpha) : 0.f;
            w3b[i] = f2bf(q);
        }
        return;
    }
    float* dst;
    switch (tensor) {
        case 0: dst = q1t;  break;
        case 3: dst = fw1t; break;
        default: dst = fw2t; break;
    }
    for (int i = blk * 256 + threadIdx.x; i < n; i += BLOCKS_PER_TENSOR * 256) {
        float w = src[i];
        float aw = fabsf(w);
        float q = (aw > delta) ? (w > 0.f ? alpha : -alpha) : 0.f;
        int o = i / K;
        int k = i - o * K;
        dst[k * O + o] = q;
    }
}

// ---------------------------------------------------------------------------
// conv1: x[1024,1,32,32] * q1t[25][32] -> tanh -> pool2
//        -> p1h bf16 NHWC [n][196][32]
__global__ __launch_bounds__(256)
void conv1_kernel(const float* __restrict__ x, const float* __restrict__ q1t,
                  const float* __restrict__ b1, ushort* __restrict__ p1h) {
    const int n = blockIdx.x;
    __shared__ float sx[1024];
    __shared__ float sw[800];
    const int t = threadIdx.x;
    {
        const float4* src = (const float4*)(x + (size_t)n * 1024);
        if (t < 256) ((float4*)sx)[t] = src[t];
        if (t < 200) ((float4*)sw)[t] = ((const float4*)q1t)[t];
    }
    __syncthreads();

    const int ocg  = t >> 5;
    const int pos0 = t & 31;
    float bias[4];
    #pragma unroll
    for (int o = 0; o < 4; ++o) bias[o] = b1[ocg * 4 + o];

    for (int pos = pos0; pos < 196; pos += 32) {
        const int ph = pos / 14, pw = pos - ph * 14;
        const int r0 = 2 * ph, c0 = 2 * pw;
        float acc[4][4] = {};
        const float4* wp = (const float4*)sw + ocg;
        #pragma unroll
        for (int kh = 0; kh < 5; ++kh) {
            const float* xr = sx + (r0 + kh) * 32 + c0;
            #pragma unroll
            for (int kw = 0; kw < 5; ++kw) {
                const float4 w4 = *wp; wp += 8;
                const float x00 = xr[kw],      x01 = xr[kw + 1];
                const float x10 = xr[kw + 32], x11 = xr[kw + 33];
                acc[0][0] = fmaf(w4.x, x00, acc[0][0]);
                acc[0][1] = fmaf(w4.x, x01, acc[0][1]);
                acc[0][2] = fmaf(w4.x, x10, acc[0][2]);
                acc[0][3] = fmaf(w4.x, x11, acc[0][3]);
                acc[1][0] = fmaf(w4.y, x00, acc[1][0]);
                acc[1][1] = fmaf(w4.y, x01, acc[1][1]);
                acc[1][2] = fmaf(w4.y, x10, acc[1][2]);
                acc[1][3] = fmaf(w4.y, x11, acc[1][3]);
                acc[2][0] = fmaf(w4.z, x00, acc[2][0]);
                acc[2][1] = fmaf(w4.z, x01, acc[2][1]);
                acc[2][2] = fmaf(w4.z, x10, acc[2][2]);
                acc[2][3] = fmaf(w4.z, x11, acc[2][3]);
                acc[3][0] = fmaf(w4.w, x00, acc[3][0]);
                acc[3][1] = fmaf(w4.w, x01, acc[3][1]);
                acc[3][2] = fmaf(w4.w, x10, acc[3][2]);
                acc[3][3] = fmaf(w4.w, x11, acc[3][3]);
            }
        }
        ushort4 qv;
        {
            float m0 = fmaxf(fmaxf(acc[0][0], acc[0][1]), fmaxf(acc[0][2], acc[0][3]));
            float m1 = fmaxf(fmaxf(acc[1][0], acc[1][1]), fmaxf(acc[1][2], acc[1][3]));
            float m2 = fmaxf(fmaxf(acc[2][0], acc[2][1]), fmaxf(acc[2][2], acc[2][3]));
            float m3 = fmaxf(fmaxf(acc[3][0], acc[3][1]), fmaxf(acc[3][2], acc[3][3]));
            qv.x = f2bf(tanhf(m0 + bias[0]));
            qv.y = f2bf(tanhf(m1 + bias[1]));
            qv.z = f2bf(tanhf(m2 + bias[2]));
            qv.w = f2bf(tanhf(m3 + bias[3]));
        }
        *(ushort4*)(p1h + ((size_t)n * 196 + pos) * 32 + ocg * 4) = qv;
    }
}

// ---------------------------------------------------------------------------
// conv2 as MFMA implicit GEMM (M=100 px, N=64 oc, K=800).
template<int TBASE, int TCNT>
__device__ __forceinline__ void conv2_phase(
        const ushort* __restrict__ w2b, const ushort* sxt,
        int n0, int mt0, int lane, f32x4 acc[4][2]) {
    const int col = lane & 15, quad = lane >> 4;
    bf16x8 bfr[TCNT][2];
    #pragma unroll
    for (int i = 0; i < TCNT; ++i) {
        const int tap = TBASE + i;
        #pragma unroll
        for (int np = 0; np < 2; ++np) {
            const int oc = n0 + np * 16 + col;
            bfr[i][np] = *(const bf16x8*)(w2b + (oc * 25 + tap) * 32 + quad * 8);
        }
    }
    #pragma unroll
    for (int mi = 0; mi < 4; ++mi) {
        int m = (mt0 + mi) * 16 + col;
        m = m < 100 ? m : 99;
        const int oh = m / 10, ow = m - oh * 10;
        const ushort* abase = sxt + (oh * 14 + ow) * 40 + quad * 8;
        #pragma unroll
        for (int i = 0; i < TCNT; ++i) {
            const int tap = TBASE + i;
            const int kh = tap / 5, kw = tap - kh * 5;
            bf16x8 af = *(const bf16x8*)(abase + (kh * 14 + kw) * 40);
            acc[mi][0] = __builtin_amdgcn_mfma_f32_16x16x32_bf16(af, bfr[i][0], acc[mi][0], 0, 0, 0);
            acc[mi][1] = __builtin_amdgcn_mfma_f32_16x16x32_bf16(af, bfr[i][1], acc[mi][1], 0, 0, 0);
        }
    }
}

__global__ __launch_bounds__(256)
void conv2_mfma(const ushort* __restrict__ p1h, const ushort* __restrict__ w2b,
                const float* __restrict__ b2, ushort* __restrict__ p2b) {
    __shared__ ushort sxt[196 * 40];   // stride 40 -> 2-way-max banks
    __shared__ float  cbuf[64 * 100];  // conv out [oc][pix]
    const int n = blockIdx.x;
    const int t = threadIdx.x;

    {   // stage NHWC image tile
        const float4* src = (const float4*)(p1h + (size_t)n * 6272);
        for (int c = t; c < 784; c += 256) {
            const int pix = c >> 2, icq = c & 3;
            *(float4*)(&sxt[pix * 40 + icq * 8]) = src[c];
        }
    }
    __syncthreads();

    const int wave = t >> 6, lane = t & 63;
    const int n0  = (wave & 1) * 32;
    const int mt0 = (wave >> 1) * 4;
    f32x4 acc[4][2] = {};

    conv2_phase<0, 13>(w2b, sxt, n0, mt0, lane, acc);
    conv2_phase<13, 12>(w2b, sxt, n0, mt0, lane, acc);

    {   // C -> LDS [oc][pix]
        const int col = lane & 15, quad = lane >> 4;
        #pragma unroll
        for (int mi = 0; mi < 4; ++mi) {
            const int mrow = (mt0 + mi) * 16 + quad * 4;
            if (mrow < 100) {
                #pragma unroll
                for (int np = 0; np < 2; ++np) {
                    const int oc = n0 + np * 16 + col;
                    *(f32x4*)(&cbuf[oc * 100 + mrow]) = acc[mi][np];
                }
            }
        }
    }
    __syncthreads();

    // pool 2x2 + bias + tanh -> p2b bf16 [n][1600] (k = oc*25 + pix)
    for (int idx = t; idx < 1600; idx += 256) {
        const int oc = idx / 25, r = idx - oc * 25;
        const int ph = r / 5, pw = r - ph * 5;
        const float* c0 = &cbuf[oc * 100 + ph * 20 + pw * 2];
        float m = fmaxf(fmaxf(c0[0], c0[1]), fmaxf(c0[10], c0[11]));
        p2b[(size_t)n * 1600 + idx] = f2bf(tanhf(m + b2[oc]));
    }
}

// ---------------------------------------------------------------------------
// conv3 as MFMA GEMM: h3[1024][120] = tanh(P2[1024][1600] x W3[120][1600]^T + b3)
// Grid 256 = 64 m-tiles x 4 oc-pairs. Waves split K 13/13/12/12; LDS reduce.
template<int STEPS>
__device__ __forceinline__ void conv3_chunk(const ushort* Abase, const ushort* B0,
                                            const ushort* B1, f32x4& acc0, f32x4& acc1) {
    #pragma unroll
    for (int s = 0; s < STEPS; ++s) {
        bf16x8 af = *(const bf16x8*)(Abase + s * 32);
        bf16x8 b0 = *(const bf16x8*)(B0 + s * 32);
        bf16x8 b1 = *(const bf16x8*)(B1 + s * 32);
        acc0 = __builtin_amdgcn_mfma_f32_16x16x32_bf16(af, b0, acc0, 0, 0, 0);
        acc1 = __builtin_amdgcn_mfma_f32_16x16x32_bf16(af, b1, acc1, 0, 0, 0);
    }
}

__global__ __launch_bounds__(256)
void conv3_mfma(const ushort* __restrict__ p2b, const ushort* __restrict__ w3b,
                const float* __restrict__ b3, float* __restrict__ h3) {
    __shared__ float red[4][64][8];   // [wave][lane][np*4+reg]
    const int t = threadIdx.x;
    const int wave = t >> 6, lane = t & 63;
    const int mt = blockIdx.x >> 2;       // 0..63
    const int npair = blockIdx.x & 3;     // 0..3
    const int col = lane & 15, quad = lane >> 4;
    const int kstart = (wave < 2) ? wave * 13 : 26 + (wave - 2) * 12;  // 0,13,26,38

    const ushort* Abase = p2b + (size_t)(mt * 16 + col) * 1600 + kstart * 32 + quad * 8;
    const ushort* B0 = w3b + (size_t)(npair * 32 + col) * 1600 + kstart * 32 + quad * 8;
    const ushort* B1 = B0 + 16 * 1600;

    f32x4 acc0 = {}, acc1 = {};
    if (wave < 2) conv3_chunk<13>(Abase, B0, B1, acc0, acc1);
    else          conv3_chunk<12>(Abase, B0, B1, acc0, acc1);

    #pragma unroll
    for (int r = 0; r < 4; ++r) {
        red[wave][lane][r]     = acc0[r];
        red[wave][lane][4 + r] = acc1[r];
    }
    __syncthreads();

    {   // thread t: lane l = t&63, reg vh = t>>6; handles np = 0 and 1
        const int l = t & 63, vh = t >> 6;
        const int lcol = l & 15, lquad = l >> 4;
        const int img = mt * 16 + lquad * 4 + vh;
        #pragma unroll
        for (int j = 0; j < 2; ++j) {
            const int v = j * 4 + vh;
            float s = red[0][l][v] + red[1][l][v] + red[2][l][v] + red[3][l][v];
            const int oc = npair * 32 + j * 16 + lcol;
            if (oc < 120) h3[(size_t)img * 120 + oc] = tanhf(s + b3[oc]);
        }
    }
}

// ---------------------------------------------------------------------------
__global__ __launch_bounds__(128)
void fc_kernel(const float* __restrict__ h3, const float* __restrict__ fw1t,
               const float* __restrict__ fb1, const float* __restrict__ fw2t,
               const float* __restrict__ fb2, float* __restrict__ out) {
    const int n = blockIdx.x;
    __shared__ float sh[120];
    __shared__ float sh4[84];
    __shared__ float sl[10];
    const int t = threadIdx.x;
    if (t < 120) sh[t] = h3[(size_t)n * 120 + t];
    __syncthreads();
    if (t < 84) {
        float a = fb1[t];
        #pragma unroll 4
        for (int k = 0; k < 120; ++k) a = fmaf(fw1t[k * 84 + t], sh[k], a);
        sh4[t] = tanhf(a);
    }
    __syncthreads();
    if (t < 10) {
        float a = fb2[t];
        #pragma unroll 4
        for (int k = 0; k < 84; ++k) a = fmaf(fw2t[k * 10 + t], sh4[k], a);
        sl[t] = a;
        out[(size_t)n * 10 + t] = a;
    }
    __syncthreads();
    if (t < 10) {
        float m = -INFINITY;
        #pragma unroll
        for (int i = 0; i < 10; ++i) m = fmaxf(m, sl[i]);
        float s = 0.f;
        #pragma unroll
        for (int i = 0; i < 10; ++i) s += expf(sl[i] - m);
        out[10240 + (size_t)n * 10 + t] = expf(sl[t] - m) / s;
    }
}

// ---------------------------------------------------------------------------
extern "C" void kernel_launch(void* const* d_in, const int* in_sizes, int n_in,
                              void* d_out, int out_size, void* d_ws, size_t ws_size,
                              hipStream_t stream) {
    const float* x   = (const float*)d_in[0];
    const float* w1  = (const float*)d_in[1];
    const float* b1  = (const float*)d_in[2];
    const float* w2  = (const float*)d_in[3];
    const float* b2  = (const float*)d_in[4];
    const float* w3  = (const float*)d_in[5];
    const float* b3  = (const float*)d_in[6];
    const float* fw1 = (const float*)d_in[7];
    const float* fb1 = (const float*)d_in[8];
    const float* fw2 = (const float*)d_in[9];
    const float* fb2 = (const float*)d_in[10];

    float* ws = (float*)d_ws;
    float*  q1t  = ws + OFF_Q1T;
    ushort* w2b  = (ushort*)(ws + OFF_W2B);
    ushort* w3b  = (ushort*)(ws + OFF_W3B);
    float*  fw1t = ws + OFF_FW1T;
    float*  fw2t = ws + OFF_FW2T;
    ushort* p1h  = (ushort*)(ws + OFF_P1H);
    ushort* p2b  = (ushort*)(ws + OFF_P2B);
    float*  h3   = ws + OFF_H3;
    float*  acc  = ws + OFF_ACC;
    float*  out  = (float*)d_out;

    hipMemsetAsync(acc, 0, 16 * sizeof(float), stream);

    tern_reduce_abs <<<5 * BLOCKS_PER_TENSOR, 256, 0, stream>>>(w1, w2, w3, fw1, fw2, acc);
    tern_reduce_mask<<<5 * BLOCKS_PER_TENSOR, 256, 0, stream>>>(w1, w2, w3, fw1, fw2, acc);
    tern_quantize   <<<5 * BLOCKS_PER_TENSOR, 256, 0, stream>>>(w1, w2, w3, fw1, fw2,
                                                                q1t, w2b, w3b, fw1t, fw2t, acc);
    conv1_kernel<<<1024, 256, 0, stream>>>(x, q1t, b1, p1h);
    conv2_mfma  <<<1024, 256, 0, stream>>>(p1h, w2b, b2, p2b);
    conv3_mfma  <<<256, 256, 0, stream>>>(p2b, w3b, b3, h3);
    fc_kernel   <<<1024, 128, 0, stream>>>(h3, fw1t, fb1, fw2t, fb2, out);
}